// Round 7
// baseline (117.347 us; speedup 1.0000x reference)
//
#include <hip/hip_runtime.h>
#include <hip/hip_bf16.h>
#include <stdint.h>

typedef __attribute__((ext_vector_type(8))) __bf16 bf16x8;
typedef __attribute__((ext_vector_type(16))) float floatx16;

#if __has_builtin(__builtin_amdgcn_exp2f)
#define EXP2F(x) __builtin_amdgcn_exp2f(x)
#else
#define EXP2F(x) exp2f(x)
#endif

// sqrt(2*log2(e)): baked into normalized rows so dot = 2*log2(e)*cos and
// sim = exp2(dot) = exp(cos/0.5) with zero epilogue multiplies.
#define SCALE_SQRT 1.69864359f
#define JCH 16   // j-chunks; grid = 16 x 64 = 1024 blocks
#define TPW 16   // 32-col j-tiles per wave (8192/JCH/32)

// ---- sort pass 1: decode labels (int64 hedge), per-256-chunk hist + ranks ----
__global__ __launch_bounds__(256) void k_sort1(const int* __restrict__ raw,
                                               int* __restrict__ lab,
                                               int* __restrict__ ranks,
                                               int* __restrict__ cnt, int N) {
  __shared__ int h[64];
  __shared__ int s64;
  const int r = blockIdx.x * 256 + threadIdx.x;
  if (threadIdx.x < 64) {
    h[threadIdx.x] = 0;
    const int probe = raw[2 * threadIdx.x + 1];  // odd words all 0 => int64
    const unsigned long long b = __ballot(probe != 0);
    if (threadIdx.x == 0) s64 = (b == 0ull);
  }
  __syncthreads();
  const int l = (s64 ? raw[2 * r] : raw[r]) & 63;
  lab[r] = l;
  ranks[r] = atomicAdd(&h[l], 1);
  __syncthreads();
  if (threadIdx.x < 64) cnt[blockIdx.x * 64 + threadIdx.x] = h[threadIdx.x];
}

// ---- sort pass 2: scan chunk counts -> per-chunk bases + class cumsum -------
__global__ __launch_bounds__(256) void k_scan(const int* __restrict__ cnt,
                                              int* __restrict__ base,
                                              int* __restrict__ cum, int N) {
  __shared__ int tot[64];
  const int k = threadIdx.x;
  const int nch = N >> 8;  // 32
  if (k < 64) {
    int run = 0;
    for (int c = 0; c < nch; ++c) { base[c * 64 + k] = run; run += cnt[c * 64 + k]; }
    tot[k] = run;
  }
  __syncthreads();
  if (k == 0) {
    int run = 0;
    for (int i = 0; i < 64; ++i) { cum[i] = run; run += tot[i]; }
    cum[64] = run;
  }
  __syncthreads();
  for (int i = threadIdx.x; i < nch * 64; i += 256) base[i] += cum[i & 63];
}

// ---- prep: normalize+scale+bf16, scatter to sorted row-major xb AND to
// MFMA-fragment-ordered xb2: xb2[jt][kt][lane=g2*32+n][8 elems], so a wave's
// B-fragment load is one contiguous, perfectly-coalesced 1-KB dwordx4 pass ----
__global__ __launch_bounds__(256) void k_prep(const float* __restrict__ x,
                                              const int* __restrict__ lab,
                                              const int* __restrict__ ranks,
                                              const int* __restrict__ base,
                                              ushort* __restrict__ xb,
                                              ushort* __restrict__ xb2,
                                              int* __restrict__ labs, int N) {
  const int row = (blockIdx.x * 256 + threadIdx.x) >> 6;  // one wave per row
  const int lane = threadIdx.x & 63;
  if (row >= N) return;
  const int l = lab[row];
  const int slot = base[(row >> 8) * 64 + l] + ranks[row];
  const float2 v = ((const float2*)(x + (size_t)row * 128))[lane];
  float ss = v.x * v.x + v.y * v.y;
#pragma unroll
  for (int m = 1; m < 64; m <<= 1) ss += __shfl_xor(ss, m, 64);
  const float rn = SCALE_SQRT / fmaxf(sqrtf(ss), 1e-12f);
  __hip_bfloat162 o;
  o.x = __float2bfloat16(v.x * rn);
  o.y = __float2bfloat16(v.y * rn);
  ((__hip_bfloat162*)xb)[slot * 64 + lane] = o;
  // fragment-order copy: this lane holds k = 2*lane, 2*lane+1
  const int kt = lane >> 3;             // k/16
  const int g2b = (lane >> 2) & 1;      // (k/8)&1
  const int e = (2 * lane) & 7;         // k&7 (even)
  const int jt = slot >> 5, n = slot & 31;
  ((__hip_bfloat162*)xb2)[(jt * 8 + kt) * 256 + (g2b * 32 + n) * 4 + (e >> 1)] = o;
  if (lane == 0) labs[slot] = l;
}

// ---- main: full-matrix exp(x x^T/T) row sums — NO barriers, NO LDS ----------
// Block 256 thr = 4 independent waves; wave owns 32 rows x 512-col chunk.
// A-frags in regs (loaded once). Per 32-col j-tile: 8 coalesced B-frag loads
// from xb2 -> 8 MFMA -> exp2 epilogue. Loads for t+1 issue before epilogue(t)
// (~300 cyc of cover); fine-grained vmcnt does the rest. Sorted labels =>
// pos/diag branch wave-uniform, ~1-2 of 16 tiles.
__global__ __launch_bounds__(256, 3) void k_sim(const ushort* __restrict__ xb,
                                                const ushort* __restrict__ xb2,
                                                const int* __restrict__ labs,
                                                const int* __restrict__ cum,
                                                float* __restrict__ pneg,
                                                float* __restrict__ ppos, int N) {
  const int tid = threadIdx.x;
  const int lane = tid & 63;
  const int wv = tid >> 6;
  const int l31 = lane & 31, g2 = lane >> 5;
  const int i0 = blockIdx.y * 128;
  const int rowbase = i0 + wv * 32;
  const int c = blockIdx.x;
  const int j0base = c * (TPW * 32);

  // A fragments global->reg: A[m=l31][k = kt*16 + g2*8 + e], row-major xb
  bf16x8 afr[8];
  {
    const ushort* ap = xb + (size_t)(rowbase + l31) * 128 + g2 * 8;
#pragma unroll
    for (int kt = 0; kt < 8; ++kt) afr[kt] = *(const bf16x8*)(ap + kt * 16);
  }

  // wave-uniform positive column range (labels sorted => contiguous)
  const int wps = cum[labs[rowbase]];
  const int wpe = cum[labs[rowbase + 31] + 1];

  // per-lane labels of the 16 rows this lane accumulates, packed 4x8b
  // C/D 32x32 layout: col = lane&31, row = (reg&3) + 8*(reg>>2) + 4*(lane>>5)
  int li_pack[4] = {0, 0, 0, 0};
#pragma unroll
  for (int t = 0; t < 16; ++t) {
    const int r = (t & 3) + 8 * (t >> 2) + 4 * g2;
    li_pack[t >> 2] |= labs[rowbase + r] << ((t & 3) * 8);
  }

  float neg[16], pos[16];
#pragma unroll
  for (int t = 0; t < 16; ++t) { neg[t] = 0.0f; pos[t] = 0.0f; }

  // B-frag base for this lane: xb2 + tile*4096 + kt*512 + lane*8 (ushort units)
  const ushort* bbase = xb2 + (size_t)(j0base >> 5) * 4096 + lane * 8;

  bf16x8 bfr[8];
#pragma unroll
  for (int kt = 0; kt < 8; ++kt)
    bfr[kt] = *(const bf16x8*)(bbase + kt * 512);

  for (int t = 0; t < TPW; ++t) {
    const int j0 = j0base + t * 32;

    floatx16 acc = (floatx16)(0.0f);
#pragma unroll
    for (int kt = 0; kt < 8; ++kt)
      acc = __builtin_amdgcn_mfma_f32_32x32x16_bf16(afr[kt], bfr[kt], acc, 0, 0, 0);

    // issue next tile's B loads now — they land under the epilogue
    if (t + 1 < TPW) {
      const ushort* bn = bbase + (size_t)(t + 1) * 4096;
#pragma unroll
      for (int kt = 0; kt < 8; ++kt)
        bfr[kt] = *(const bf16x8*)(bn + kt * 512);
    }

    const bool posT = (j0 < wpe) && (j0 + 32 > wps);  // wave-uniform
    if (!posT) {
#pragma unroll
      for (int reg = 0; reg < 16; ++reg)
        neg[reg] += EXP2F(acc[reg]);
    } else {
      const int lj = labs[j0 + l31];
      const bool dg = (j0 == rowbase);  // 32-aligned both => exact tile match
#pragma unroll
      for (int reg = 0; reg < 16; ++reg) {
        float e = EXP2F(acc[reg]);
        if (dg) {
          const int ir = (reg & 3) + 8 * (reg >> 2) + 4 * g2;
          if (ir == l31) e = 0.0f;  // self-similarity excluded exactly
        }
        const int liq = (li_pack[reg >> 2] >> ((reg & 3) * 8)) & 63;
        neg[reg] += e;
        pos[reg] += (liq == lj) ? e : 0.0f;
      }
    }
  }

  // ---- flush: wave owns its 32 rows; reduce over 32 cols, direct stores ----
#pragma unroll
  for (int t = 0; t < 16; ++t) {
    float n = neg[t], p = pos[t];
#pragma unroll
    for (int m = 1; m < 32; m <<= 1) {  // stays within each 32-lane half
      n += __shfl_xor(n, m, 64);
      p += __shfl_xor(p, m, 64);
    }
    if (l31 == 0) {
      const int r = rowbase + (t & 3) + 8 * (t >> 2) + 4 * g2;
      pneg[(size_t)c * N + r] = n;
      ppos[(size_t)c * N + r] = p;
    }
  }
}

// ---- finalize: sum partials + mean(log(neg*cnt/pos)) ------------------------
__global__ __launch_bounds__(1024) void k_final(const float* __restrict__ pneg,
                                                const float* __restrict__ ppos,
                                                const int* __restrict__ labs,
                                                const int* __restrict__ cum,
                                                float* __restrict__ out, int N) {
  double s = 0.0;
  for (int i = threadIdx.x; i < N; i += 1024) {
    float n = 0.0f, p = 0.0f;
#pragma unroll
    for (int c = 0; c < JCH; ++c) {
      n += pneg[(size_t)c * N + i];
      p += ppos[(size_t)c * N + i];
    }
    const int l = labs[i];
    const float cnt = (float)(cum[l + 1] - cum[l] - 1);
    s += (double)logf(n * cnt / p);
  }
#pragma unroll
  for (int m = 1; m < 64; m <<= 1) s += __shfl_xor(s, m, 64);
  __shared__ double wsum[16];
  if ((threadIdx.x & 63) == 0) wsum[threadIdx.x >> 6] = s;
  __syncthreads();
  if (threadIdx.x == 0) {
    double tot = 0.0;
    for (int w = 0; w < 16; ++w) tot += wsum[w];
    out[0] = (float)(tot / (double)N);
  }
}

extern "C" void kernel_launch(void* const* d_in, const int* in_sizes, int n_in,
                              void* d_out, int out_size, void* d_ws, size_t ws_size,
                              hipStream_t stream) {
  const float* x = (const float*)d_in[0];
  const int* raw_label = (const int*)d_in[1];
  const int N = in_sizes[1];  // 8192
  char* ws = (char*)d_ws;
  ushort* xb = (ushort*)ws;                          // N*128 bf16 = 2 MB (row-major)
  ushort* xb2 = xb + (size_t)N * 128;                // 2 MB (fragment-order)
  float* pneg = (float*)(xb2 + (size_t)N * 128);     // JCH*N f32
  float* ppos = pneg + (size_t)JCH * N;              // JCH*N f32
  int* lab = (int*)(ppos + (size_t)JCH * N);         // N
  int* ranks = lab + N;                              // N
  int* labs = ranks + N;                             // N (sorted labels)
  int* cnt = labs + N;                               // (N/256)*64
  int* base = cnt + (N >> 8) * 64;                   // (N/256)*64
  int* cum = base + (N >> 8) * 64;                   // 65
  float* out = (float*)d_out;

  k_sort1<<<dim3(N / 256), dim3(256), 0, stream>>>(raw_label, lab, ranks, cnt, N);
  k_scan<<<dim3(1), dim3(256), 0, stream>>>(cnt, base, cum, N);
  k_prep<<<dim3(N / 4), dim3(256), 0, stream>>>(x, lab, ranks, base, xb, xb2, labs, N);
  k_sim<<<dim3(JCH, N / 128), dim3(256), 0, stream>>>(xb, xb2, labs, cum, pneg, ppos, N);
  k_final<<<dim3(1), dim3(1024), 0, stream>>>(pneg, ppos, labs, cum, out, N);
}

// Round 8
// 111.099 us; speedup vs baseline: 1.0562x; 1.0562x over previous
//
#include <hip/hip_runtime.h>
#include <hip/hip_bf16.h>
#include <stdint.h>

typedef __attribute__((ext_vector_type(8))) __bf16 bf16x8;
typedef __attribute__((ext_vector_type(16))) float floatx16;

#if __has_builtin(__builtin_amdgcn_exp2f)
#define EXP2F(x) __builtin_amdgcn_exp2f(x)
#else
#define EXP2F(x) exp2f(x)
#endif

// sqrt(2*log2(e)): baked into normalized rows so dot = 2*log2(e)*cos and
// sim = exp2(dot) = exp(cos/0.5) with zero epilogue multiplies.
#define SCALE_SQRT 1.69864359f
#define JCH 16   // j-chunks; grid = 16 x 32 = 512 blocks (2/CU at 4 waves)
#define TPW 16   // 32-col j-tiles per chunk (8192/16/32)

// ---- sort pass 1: decode labels (int64 hedge), per-256-chunk hist + ranks ----
// cnt is TRANSPOSED: cnt[class*32 + chunk] so k_scan's per-class loads coalesce
__global__ __launch_bounds__(256) void k_sort1(const int* __restrict__ raw,
                                               int* __restrict__ lab,
                                               int* __restrict__ ranks,
                                               int* __restrict__ cnt, int N) {
  __shared__ int h[64];
  __shared__ int s64;
  const int r = blockIdx.x * 256 + threadIdx.x;
  if (threadIdx.x < 64) {
    h[threadIdx.x] = 0;
    const int probe = raw[2 * threadIdx.x + 1];  // odd words all 0 => int64
    const unsigned long long b = __ballot(probe != 0);
    if (threadIdx.x == 0) s64 = (b == 0ull);
  }
  __syncthreads();
  const int l = (s64 ? raw[2 * r] : raw[r]) & 63;
  lab[r] = l;
  ranks[r] = atomicAdd(&h[l], 1);
  __syncthreads();
  if (threadIdx.x < 64) cnt[threadIdx.x * 32 + blockIdx.x] = h[threadIdx.x];
}

// ---- sort pass 2: per-class prefix over chunks + class cumsum ---------------
__global__ __launch_bounds__(256) void k_scan(const int* __restrict__ cnt,
                                              int* __restrict__ base,
                                              int* __restrict__ cum, int N) {
  __shared__ int tot[64];
  const int k = threadIdx.x;
  const int nch = N >> 8;  // 32
  if (k < 64) {
    int run = 0;
#pragma unroll 4
    for (int c = 0; c < nch; ++c) {  // contiguous (transposed) loads
      const int v = cnt[k * 32 + c];
      base[k * 32 + c] = run;
      run += v;
    }
    tot[k] = run;
  }
  __syncthreads();
  if (k == 0) {
    int run = 0;
    for (int i = 0; i < 64; ++i) { cum[i] = run; run += tot[i]; }
    cum[64] = run;
  }
  __syncthreads();
  if (k < 64) {
    const int cb = cum[k];
#pragma unroll 4
    for (int c = 0; c < nch; ++c) base[k * 32 + c] += cb;
  }
}

// ---- prep: normalize+scale+bf16, scatter to sorted row-major xb AND to
// MFMA-fragment-ordered xb2: xb2[jt][kt][g2*32+n][8], so a wave's B-fragment
// load is one contiguous, perfectly-coalesced 1-KB dwordx4 access -------------
__global__ __launch_bounds__(256) void k_prep(const float* __restrict__ x,
                                              const int* __restrict__ lab,
                                              const int* __restrict__ ranks,
                                              const int* __restrict__ base,
                                              ushort* __restrict__ xb,
                                              ushort* __restrict__ xb2,
                                              int* __restrict__ labs, int N) {
  const int row = (blockIdx.x * 256 + threadIdx.x) >> 6;  // one wave per row
  const int lane = threadIdx.x & 63;
  if (row >= N) return;
  const int l = lab[row];
  const int slot = base[l * 32 + (row >> 8)] + ranks[row];
  const float2 v = ((const float2*)(x + (size_t)row * 128))[lane];
  float ss = v.x * v.x + v.y * v.y;
#pragma unroll
  for (int m = 1; m < 64; m <<= 1) ss += __shfl_xor(ss, m, 64);
  const float rn = SCALE_SQRT / fmaxf(sqrtf(ss), 1e-12f);
  __hip_bfloat162 o;
  o.x = __float2bfloat16(v.x * rn);
  o.y = __float2bfloat16(v.y * rn);
  ((__hip_bfloat162*)xb)[slot * 64 + lane] = o;
  // fragment-order copy: this lane holds k = 2*lane, 2*lane+1
  const int kt = lane >> 3;             // k/16
  const int g2b = (lane >> 2) & 1;      // (k/8)&1
  const int e = (2 * lane) & 7;         // k&7 (even)
  const int jt = slot >> 5, n = slot & 31;
  ((__hip_bfloat162*)xb2)[(jt * 8 + kt) * 256 + (g2b * 32 + n) * 4 + (e >> 1)] = o;
  if (lane == 0) labs[slot] = l;
}

// ---- main: full-matrix exp(x x^T/T) row sums — 64-row waves, no LDS ---------
// Block 256 thr = 4 waves x 64 rows = 256-row strip; 16 j-tiles of 32 cols.
// B traffic halved vs 32-row waves (1 MB/CU): the R7 bottleneck. A-frags in
// regs (64 VGPRs, loaded once). Bare s_barrier (no vmcnt drain — no LDS data
// dep) phase-locks the 4 waves so each 8-KB B tile is read from L1 by 3 of 4.
// B prefetch for t+1 issues after MFMA consumes bfr(t); lands under epilogue.
// Sorted labels => pos/diag branch wave-uniform (~1-2 of 16 tiles); diag tiles
// are always pos tiles, so the hot path is exp2+add only.
__global__ __launch_bounds__(256, 2) void k_sim(const ushort* __restrict__ xb,
                                                const ushort* __restrict__ xb2,
                                                const int* __restrict__ labs,
                                                const int* __restrict__ cum,
                                                float* __restrict__ pneg,
                                                float* __restrict__ ppos, int N) {
  const int tid = threadIdx.x;
  const int lane = tid & 63;
  const int wv = tid >> 6;
  const int l31 = lane & 31, g2 = lane >> 5;
  const int rowbase = blockIdx.y * 256 + wv * 64;
  const int c = blockIdx.x;
  const int j0base = c * (TPW * 32);

  // A fragments global->reg: A[m=l31][k = kt*16 + g2*8 + e], row-major xb
  bf16x8 afr[2][8];
#pragma unroll
  for (int mi = 0; mi < 2; ++mi) {
    const ushort* ap = xb + (size_t)(rowbase + mi * 32 + l31) * 128 + g2 * 8;
#pragma unroll
    for (int kt = 0; kt < 8; ++kt) afr[mi][kt] = *(const bf16x8*)(ap + kt * 16);
  }

  // wave-uniform positive column range (labels sorted => contiguous)
  const int wps = cum[labs[rowbase]];
  const int wpe = cum[labs[rowbase + 63] + 1];

  // per-lane labels of the 32 rows this lane accumulates, packed 4x8b
  // C/D 32x32 layout: col = lane&31, row = (reg&3) + 8*(reg>>2) + 4*(lane>>5)
  int li_pack[8] = {0, 0, 0, 0, 0, 0, 0, 0};
#pragma unroll
  for (int t = 0; t < 32; ++t) {
    const int mi = t >> 4, reg = t & 15;
    const int r = mi * 32 + (reg & 3) + 8 * (reg >> 2) + 4 * g2;
    li_pack[t >> 2] |= labs[rowbase + r] << ((t & 3) * 8);
  }

  float neg[32], pos[32];
#pragma unroll
  for (int t = 0; t < 32; ++t) { neg[t] = 0.0f; pos[t] = 0.0f; }

  // B-frag base for this lane: xb2 + tile*4096 + kt*512 + lane*8 (ushort units)
  const ushort* bbase = xb2 + (size_t)(j0base >> 5) * 4096 + lane * 8;

  bf16x8 bfr[8];
#pragma unroll
  for (int kt = 0; kt < 8; ++kt) bfr[kt] = *(const bf16x8*)(bbase + kt * 512);

  for (int t = 0; t < TPW; ++t) {
    __builtin_amdgcn_s_barrier();  // bare phase-lock: no data dep, no drain

    floatx16 a0 = (floatx16)(0.0f), a1 = (floatx16)(0.0f);
#pragma unroll
    for (int kt = 0; kt < 8; ++kt) {
      a0 = __builtin_amdgcn_mfma_f32_32x32x16_bf16(afr[0][kt], bfr[kt], a0, 0, 0, 0);
      a1 = __builtin_amdgcn_mfma_f32_32x32x16_bf16(afr[1][kt], bfr[kt], a1, 0, 0, 0);
    }

    // issue next tile's B loads now (regs free after MFMA issue); they land
    // under the ~250-cyc epilogue below
    if (t + 1 < TPW) {
      const ushort* bn = bbase + (size_t)(t + 1) * 4096;
#pragma unroll
      for (int kt = 0; kt < 8; ++kt) bfr[kt] = *(const bf16x8*)(bn + kt * 512);
    }

    const int j0 = j0base + t * 32;
    const bool posT = (j0 < wpe) && (j0 + 32 > wps);  // wave-uniform
    if (!posT) {  // hot path: exp2 + add only (diag tiles are always posT)
#pragma unroll
      for (int reg = 0; reg < 16; ++reg) {
        neg[reg] += EXP2F(a0[reg]);
        neg[16 + reg] += EXP2F(a1[reg]);
      }
    } else {
      const int lj = labs[j0 + l31];
      const bool dg0 = (j0 == rowbase);        // 32-aligned => exact tile match
      const bool dg1 = (j0 == rowbase + 32);
#pragma unroll
      for (int reg = 0; reg < 16; ++reg) {
        float e0 = EXP2F(a0[reg]);
        float e1 = EXP2F(a1[reg]);
        const int ir = (reg & 3) + 8 * (reg >> 2) + 4 * g2;
        if (dg0 && ir == l31) e0 = 0.0f;       // self-similarity excluded
        if (dg1 && ir == l31) e1 = 0.0f;
        const int q0 = (li_pack[reg >> 2] >> ((reg & 3) * 8)) & 63;
        const int q1 = (li_pack[4 + (reg >> 2)] >> ((reg & 3) * 8)) & 63;
        neg[reg] += e0;
        neg[16 + reg] += e1;
        pos[reg] += (q0 == lj) ? e0 : 0.0f;
        pos[16 + reg] += (q1 == lj) ? e1 : 0.0f;
      }
    }
  }

  // ---- flush: wave owns its 64 rows; reduce over 32 cols, direct stores ----
#pragma unroll
  for (int t = 0; t < 32; ++t) {
    float n = neg[t], p = pos[t];
#pragma unroll
    for (int m = 1; m < 32; m <<= 1) {  // stays within each 32-lane half
      n += __shfl_xor(n, m, 64);
      p += __shfl_xor(p, m, 64);
    }
    if (l31 == 0) {
      const int mi = t >> 4, reg = t & 15;
      const int r = rowbase + mi * 32 + (reg & 3) + 8 * (reg >> 2) + 4 * g2;
      pneg[(size_t)c * N + r] = n;
      ppos[(size_t)c * N + r] = p;
    }
  }
}

// ---- finalize: sum partials + mean(log(neg*cnt/pos)) ------------------------
__global__ __launch_bounds__(1024) void k_final(const float* __restrict__ pneg,
                                                const float* __restrict__ ppos,
                                                const int* __restrict__ labs,
                                                const int* __restrict__ cum,
                                                float* __restrict__ out, int N) {
  double s = 0.0;
  for (int i = threadIdx.x; i < N; i += 1024) {
    float n = 0.0f, p = 0.0f;
#pragma unroll
    for (int c = 0; c < JCH; ++c) {
      n += pneg[(size_t)c * N + i];
      p += ppos[(size_t)c * N + i];
    }
    const int l = labs[i];
    const float cnt = (float)(cum[l + 1] - cum[l] - 1);
    s += (double)logf(n * cnt / p);
  }
#pragma unroll
  for (int m = 1; m < 64; m <<= 1) s += __shfl_xor(s, m, 64);
  __shared__ double wsum[16];
  if ((threadIdx.x & 63) == 0) wsum[threadIdx.x >> 6] = s;
  __syncthreads();
  if (threadIdx.x == 0) {
    double tot = 0.0;
    for (int w = 0; w < 16; ++w) tot += wsum[w];
    out[0] = (float)(tot / (double)N);
  }
}

extern "C" void kernel_launch(void* const* d_in, const int* in_sizes, int n_in,
                              void* d_out, int out_size, void* d_ws, size_t ws_size,
                              hipStream_t stream) {
  const float* x = (const float*)d_in[0];
  const int* raw_label = (const int*)d_in[1];
  const int N = in_sizes[1];  // 8192
  char* ws = (char*)d_ws;
  ushort* xb = (ushort*)ws;                          // N*128 bf16 = 2 MB (row-major)
  ushort* xb2 = xb + (size_t)N * 128;                // 2 MB (fragment-order)
  float* pneg = (float*)(xb2 + (size_t)N * 128);     // JCH*N f32
  float* ppos = pneg + (size_t)JCH * N;              // JCH*N f32
  int* lab = (int*)(ppos + (size_t)JCH * N);         // N
  int* ranks = lab + N;                              // N
  int* labs = ranks + N;                             // N (sorted labels)
  int* cnt = labs + N;                               // 64*(N/256), transposed
  int* base = cnt + 64 * (N >> 8);                   // 64*(N/256), transposed
  int* cum = base + 64 * (N >> 8);                   // 65
  float* out = (float*)d_out;

  k_sort1<<<dim3(N / 256), dim3(256), 0, stream>>>(raw_label, lab, ranks, cnt, N);
  k_scan<<<dim3(1), dim3(256), 0, stream>>>(cnt, base, cum, N);
  k_prep<<<dim3(N / 4), dim3(256), 0, stream>>>(x, lab, ranks, base, xb, xb2, labs, N);
  k_sim<<<dim3(JCH, N / 256), dim3(256), 0, stream>>>(xb, xb2, labs, cum, pneg, ppos, N);
  k_final<<<dim3(1), dim3(1024), 0, stream>>>(pneg, ppos, labs, cum, out, N);
}